// Round 17
// baseline (56.319 us; speedup 1.0000x reference)
//
#include <hip/hip_runtime.h>
#include <stdint.h>

typedef __attribute__((ext_vector_type(8))) short short8v;
typedef __attribute__((ext_vector_type(4))) float float4v;

__device__ __forceinline__ unsigned short f32_to_bf16(float f) {
    union { float f; uint32_t u; } v; v.f = f;
    uint32_t u = v.u;
    u += 0x7FFFu + ((u >> 16) & 1u);
    return (unsigned short)(u >> 16);
}
__device__ __forceinline__ float bf16_to_f32(unsigned short s) {
    union { uint32_t u; float f; } v; v.u = ((uint32_t)s) << 16;
    return v.f;
}

#define T_LEN 4096
#define C_DIM 1024
#define HSZ 64

// ---------------- kernel 0: W -> Wtp (bf16, FRAGMENT-MAJOR) ----------------
__global__ void wt_kernel(const float* __restrict__ Wq, const float* __restrict__ Wk,
                          const float* __restrict__ Wv, unsigned short* __restrict__ Wtp) {
    int idx = blockIdx.x * blockDim.x + threadIdx.x;   // 0 .. 196607
    int e    = idx & 7;
    int lane = (idx >> 3) & 63;
    int ks   = (idx >> 9) & 31;
    int ct   = idx >> 14;
    int g = lane >> 4, c = lane & 15;
    int k   = ks * 32 + g * 8 + e;
    int col = (ct & 3) * 16 + c;
    int m   = ct >> 2;
    const float* W = (m == 0) ? Wq : ((m == 1) ? Wk : Wv);
    Wtp[idx] = f32_to_bf16(W[(size_t)k * 64 + col]);
}

// ---------------- kernel 1: QKV projection (R16, unchanged) ----------------
#define XCH 264   // 256 + 8 pad

__global__ __launch_bounds__(512) void qkv_kernel(
    const float* __restrict__ x, const unsigned short* __restrict__ Wtp,
    unsigned short* __restrict__ qo, unsigned short* __restrict__ kp,
    unsigned short* __restrict__ vp)
{
    __shared__ __align__(16) unsigned short xs2[2][32 * XCH];   // 33 KB
    __shared__ float part[4][2][3][64][4];                       // 24.6 KB split-K combine

    const int tid = threadIdx.x;
    const int bid = (int)blockIdx.x;
    const int batch = (bid >> 1) & 3;        // XCD-pinned (bid%8 -> XCD)
    const int q0    = bid & 1;
    const int hi    = bid >> 3;              // [0,64)
    const int rg    = hi * 2 + q0;           // [0,128) row-group of 32
    const int row0  = batch * 4096 + rg * 32;   // global row base (32-aligned)

    const int wave = tid >> 6, lane = tid & 63;
    const int wq = wave & 3, wh = wave >> 2;
    const int g = lane >> 4, c = lane & 15;

    float4 ld[4];
    auto LOADX = [&](int cs) {
        #pragma unroll
        for (int i = 0; i < 4; ++i) {
            int f = i * 512 + tid;           // 2048 f4 per 32x256 chunk
            int row = f >> 6, c4 = f & 63;
            ld[i] = *((const float4*)x + (size_t)(row0 + row) * 256 + cs * 64 + c4);
        }
    };
    auto WRITEX = [&](int buf) {
        #pragma unroll
        for (int i = 0; i < 4; ++i) {
            int f = i * 512 + tid;
            int row = f >> 6, c4 = f & 63;
            union { unsigned short s[4]; uint64_t u; } pk;
            pk.s[0] = f32_to_bf16(ld[i].x); pk.s[1] = f32_to_bf16(ld[i].y);
            pk.s[2] = f32_to_bf16(ld[i].z); pk.s[3] = f32_to_bf16(ld[i].w);
            *(uint64_t*)(&xs2[buf][row * XCH + c4 * 4]) = pk.u;
        }
    };

    LOADX(0);
    WRITEX(0);
    __syncthreads();

    float4v acc[2][3];
    #pragma unroll
    for (int rt = 0; rt < 2; ++rt)
        #pragma unroll
        for (int t = 0; t < 3; ++t) acc[rt][t] = (float4v){0,0,0,0};

    const unsigned short* wp0 = Wtp + (size_t)((wq * 3 + 0) * 32) * 512 + lane * 8;
    const unsigned short* wp1 = Wtp + (size_t)((wq * 3 + 1) * 32) * 512 + lane * 8;
    const unsigned short* wp2 = Wtp + (size_t)((wq * 3 + 2) * 32) * 512 + lane * 8;

    for (int cs = 0; cs < 4; ++cs) {
        if (cs < 3) LOADX(cs + 1);
        const int buf = cs & 1;
        #pragma unroll
        for (int ksi = 0; ksi < 4; ++ksi) {
            const int kc = 2 * ksi + wh;
            const int ks = cs * 8 + kc;
            const int koff = kc * 32 + g * 8;
            short8v a0 = *(const short8v*)(&xs2[buf][(0 * 16 + c) * XCH + koff]);
            short8v a1 = *(const short8v*)(&xs2[buf][(1 * 16 + c) * XCH + koff]);
            short8v b0 = *(const short8v*)(wp0 + (size_t)ks * 512);
            short8v b1 = *(const short8v*)(wp1 + (size_t)ks * 512);
            short8v b2 = *(const short8v*)(wp2 + (size_t)ks * 512);
            acc[0][0] = __builtin_amdgcn_mfma_f32_16x16x32_bf16(a0, b0, acc[0][0], 0, 0, 0);
            acc[0][1] = __builtin_amdgcn_mfma_f32_16x16x32_bf16(a0, b1, acc[0][1], 0, 0, 0);
            acc[0][2] = __builtin_amdgcn_mfma_f32_16x16x32_bf16(a0, b2, acc[0][2], 0, 0, 0);
            acc[1][0] = __builtin_amdgcn_mfma_f32_16x16x32_bf16(a1, b0, acc[1][0], 0, 0, 0);
            acc[1][1] = __builtin_amdgcn_mfma_f32_16x16x32_bf16(a1, b1, acc[1][1], 0, 0, 0);
            acc[1][2] = __builtin_amdgcn_mfma_f32_16x16x32_bf16(a1, b2, acc[1][2], 0, 0, 0);
        }
        if (cs < 3) {
            __syncthreads();
            WRITEX(buf ^ 1);
            __syncthreads();
        }
    }

    __syncthreads();
    if (wh == 1) {
        #pragma unroll
        for (int rt = 0; rt < 2; ++rt)
            #pragma unroll
            for (int t = 0; t < 3; ++t)
                #pragma unroll
                for (int j = 0; j < 4; ++j)
                    part[wq][rt][t][lane][j] = acc[rt][t][j];
    }
    __syncthreads();
    if (wh == 0) {
        #pragma unroll
        for (int rt = 0; rt < 2; ++rt) {
            const int row0t = row0 + rt * 16;
            #pragma unroll
            for (int t = 0; t < 3; ++t) {
                float4v av = acc[rt][t];
                #pragma unroll
                for (int j = 0; j < 4; ++j) av[j] += part[wq][rt][t][lane][j];
                int ct = wq * 3 + t;
                int m = ct >> 2, hcol = (ct & 3) * 16 + c;
                if (m == 2) {
                    const int r0 = row0t + g * 4;
                    const int b  = r0 >> 12;
                    const int s0_ = r0 & 4095;
                    const int t2h = s0_ >> 5;
                    const int gv  = (s0_ >> 3) & 3;
                    const int e0  = s0_ & 7;
                    union { unsigned short s[4]; uint64_t u; } pk;
                    #pragma unroll
                    for (int j = 0; j < 4; ++j) pk.s[j] = f32_to_bf16(av[j]);
                    *(uint64_t*)(vp + (size_t)b * 262144 + t2h * 2048 + (ct & 3) * 512
                                    + (gv * 16 + c) * 8 + e0) = pk.u;
                } else if (m == 1) {
                    const int fbase = ((row0t & 4095) >> 6) * 8 + (((row0t & 4095) >> 4) & 3) * 2 + (hcol >> 5);
                    const int b = row0t >> 12;
                    unsigned short* kb = kp + (size_t)b * 262144 + (size_t)fbase * 512
                                         + (((hcol >> 3) & 3) * 16) * 8 + (hcol & 7);
                    #pragma unroll
                    for (int j = 0; j < 4; ++j)
                        kb[(g * 4 + j) * 8] = f32_to_bf16(av[j]);
                } else {
                    float sc = 0.125f;
                    #pragma unroll
                    for (int j = 0; j < 4; ++j)
                        qo[(size_t)(row0t + g * 4 + j) * 64 + hcol] = f32_to_bf16(av[j] * sc);
                }
            }
        }
    }
}

// ---------------- kernel 2: causal flash attention ----------------
// 512 blocks = (batch, qb) 32-row strips; 8 waves = 8 KV-slices; each wave
// computes BOTH 16-row halves per K/V fragment load (L2 K/V traffic halved).
// Swapped QK^T (lane-local softmax), frag-major kp/vp, K register ping-pong.
#define PLD 72

__global__ __launch_bounds__(512) void attn_kernel(
    const unsigned short* __restrict__ qi, const unsigned short* __restrict__ kp,
    const unsigned short* __restrict__ vp, float* __restrict__ out)
{
    __shared__ __align__(16) unsigned short Ps[8][2][16 * PLD];  // per-wave, per-half P
    __shared__ unsigned short CombO[2][7][16][64];               // bf16 partial O
    __shared__ float CombM[2][7][16];
    __shared__ float CombL[2][7][16];

    const int tid  = threadIdx.x;
    const int wave = tid >> 6, lane = tid & 63;
    const int g = lane >> 4, c = lane & 15;

    const int bid   = (int)blockIdx.x;
    const int q0    = bid & 1;
    const int batch = (bid >> 1) & 3;     // bid%8 -> XCD; pair {2b,2b+1} = batch b
    const int hi    = bid >> 3;           // [0,64)
    const int qb    = 127 - (2 * hi + q0);   // LPT: descending work with bid

    const int rb0 = qb * 32, rb1 = qb * 32 + 16;
    const int nt0 = ((rb0 + 15) >> 6) + 1;
    const int nt1 = ((rb1 + 15) >> 6) + 1;
    const size_t bo  = (size_t)batch * T_LEN * HSZ;
    const size_t bov = (size_t)batch * 262144;

    short8v qf00 = *(const short8v*)(qi + bo + (size_t)(rb0 + c) * 64 +  0 + g * 8);
    short8v qf01 = *(const short8v*)(qi + bo + (size_t)(rb0 + c) * 64 + 32 + g * 8);
    short8v qf10 = *(const short8v*)(qi + bo + (size_t)(rb1 + c) * 64 +  0 + g * 8);
    short8v qf11 = *(const short8v*)(qi + bo + (size_t)(rb1 + c) * 64 + 32 + g * 8);

    float4v acc0[4], acc1[4];
    #pragma unroll
    for (int i = 0; i < 4; ++i) { acc0[i] = (float4v){0,0,0,0}; acc1[i] = (float4v){0,0,0,0}; }
    float m0 = -3e38f, m1 = -3e38f, l0 = 0.f, l1 = 0.f;

    unsigned short* Pw0 = &Ps[wave][0][0];
    unsigned short* Pw1 = &Ps[wave][1][0];

    short8v kf[8], kn[8];

    auto LOADK = [&](int t, short8v* kd) {
        #pragma unroll
        for (int f = 0; f < 8; ++f)
            kd[f] = *(const short8v*)(kp + bov + (size_t)(t * 8 + f) * 512 + lane * 8);
    };

    auto SMAX = [&](float4v* sa, float& mr, float& ls, float4v* ac) {
        float mxA = fmaxf(fmaxf(sa[0][0], sa[0][1]), fmaxf(sa[0][2], sa[0][3]));
        float mxB = fmaxf(fmaxf(sa[1][0], sa[1][1]), fmaxf(sa[1][2], sa[1][3]));
        float mxC = fmaxf(fmaxf(sa[2][0], sa[2][1]), fmaxf(sa[2][2], sa[2][3]));
        float mxD = fmaxf(fmaxf(sa[3][0], sa[3][1]), fmaxf(sa[3][2], sa[3][3]));
        float mx = fmaxf(fmaxf(mxA, mxB), fmaxf(mxC, mxD));
        mx = fmaxf(mx, __shfl_xor(mx, 16, 64));
        mx = fmaxf(mx, __shfl_xor(mx, 32, 64));
        const float nm = fmaxf(mr, mx);
        const float al = __expf(mr - nm);
        mr = nm;
        float ps = 0.f;
        #pragma unroll
        for (int ct = 0; ct < 4; ++ct)
            #pragma unroll
            for (int j = 0; j < 4; ++j) {
                float p = __expf(sa[ct][j] - nm);
                sa[ct][j] = p;
                ps += p;
            }
        ls = ls * al + ps;
        #pragma unroll
        for (int dt = 0; dt < 4; ++dt)
            #pragma unroll
            for (int j = 0; j < 4; ++j) ac[dt][j] *= al;
    };

    auto PWRITE = [&](unsigned short* Pw, const float4v* sa) {
        #pragma unroll
        for (int ct = 0; ct < 4; ++ct) {
            union { unsigned short s[4]; uint64_t u; } pk4;
            #pragma unroll
            for (int j = 0; j < 4; ++j) pk4.s[j] = f32_to_bf16(sa[ct][j]);
            *(uint64_t*)(&Pw[c * PLD + ct * 16 + g * 4]) = pk4.u;
        }
    };

    auto TILE2 = [&](int t, const short8v* kb) {
        const int s0 = t * 64;
        const bool h0 = t < nt0;

        float4v sa0[4], sa1[4];
        if (h0) {
            #pragma unroll
            for (int ct = 0; ct < 4; ++ct) {
                float4v z = {0, 0, 0, 0};
                z = __builtin_amdgcn_mfma_f32_16x16x32_bf16(kb[ct * 2 + 0], qf00, z, 0, 0, 0);
                sa0[ct] = __builtin_amdgcn_mfma_f32_16x16x32_bf16(kb[ct * 2 + 1], qf01, z, 0, 0, 0);
            }
        }
        #pragma unroll
        for (int ct = 0; ct < 4; ++ct) {
            float4v z = {0, 0, 0, 0};
            z = __builtin_amdgcn_mfma_f32_16x16x32_bf16(kb[ct * 2 + 0], qf10, z, 0, 0, 0);
            sa1[ct] = __builtin_amdgcn_mfma_f32_16x16x32_bf16(kb[ct * 2 + 1], qf11, z, 0, 0, 0);
        }

        short8v vf0[4];   // shared across both halves
        #pragma unroll
        for (int dt = 0; dt < 4; ++dt)
            vf0[dt] = *(const short8v*)(vp + bov + (size_t)(t * 8 + dt) * 512 + lane * 8);

        if (h0 && s0 + 63 > rb0) {
            #pragma unroll
            for (int ct = 0; ct < 4; ++ct)
                #pragma unroll
                for (int j = 0; j < 4; ++j)
                    if (s0 + ct * 16 + g * 4 + j > rb0 + c) sa0[ct][j] = -3e38f;
        }
        if (s0 + 63 > rb1) {
            #pragma unroll
            for (int ct = 0; ct < 4; ++ct)
                #pragma unroll
                for (int j = 0; j < 4; ++j)
                    if (s0 + ct * 16 + g * 4 + j > rb1 + c) sa1[ct][j] = -3e38f;
        }

        if (h0) SMAX(sa0, m0, l0, acc0);
        SMAX(sa1, m1, l1, acc1);

        if (h0) PWRITE(Pw0, sa0);
        PWRITE(Pw1, sa1);

        short8v vf1[4];
        #pragma unroll
        for (int dt = 0; dt < 4; ++dt)
            vf1[dt] = *(const short8v*)(vp + bov + (size_t)(t * 8 + 4 + dt) * 512 + lane * 8);

        short8v pa10 = *(const short8v*)(&Pw1[c * PLD +  0 + g * 8]);
        short8v pa11 = *(const short8v*)(&Pw1[c * PLD + 32 + g * 8]);
        #pragma unroll
        for (int dt = 0; dt < 4; ++dt)
            acc1[dt] = __builtin_amdgcn_mfma_f32_16x16x32_bf16(vf0[dt], pa10, acc1[dt], 0, 0, 0);
        #pragma unroll
        for (int dt = 0; dt < 4; ++dt)
            acc1[dt] = __builtin_amdgcn_mfma_f32_16x16x32_bf16(vf1[dt], pa11, acc1[dt], 0, 0, 0);

        if (h0) {
            short8v pa00 = *(const short8v*)(&Pw0[c * PLD +  0 + g * 8]);
            short8v pa01 = *(const short8v*)(&Pw0[c * PLD + 32 + g * 8]);
            #pragma unroll
            for (int dt = 0; dt < 4; ++dt)
                acc0[dt] = __builtin_amdgcn_mfma_f32_16x16x32_bf16(vf0[dt], pa00, acc0[dt], 0, 0, 0);
            #pragma unroll
            for (int dt = 0; dt < 4; ++dt)
                acc0[dt] = __builtin_amdgcn_mfma_f32_16x16x32_bf16(vf1[dt], pa01, acc0[dt], 0, 0, 0);
        }
    };

    int t = wave;
    if (t < nt1) {
        LOADK(t, kf);
        while (true) {
            const bool h1 = (t + 8 < nt1);
            if (h1) LOADK(t + 8, kn);
            TILE2(t, kf);
            if (!h1) break;
            t += 8;
            const bool h2 = (t + 8 < nt1);
            if (h2) LOADK(t + 8, kf);
            TILE2(t, kn);
            if (!h2) break;
            t += 8;
        }
    }

    // reduce row sums across the 4 g-lanes (same q=c)
    l0 += __shfl_xor(l0, 16, 64); l0 += __shfl_xor(l0, 32, 64);
    l1 += __shfl_xor(l1, 16, 64); l1 += __shfl_xor(l1, 32, 64);

    // contributions: half0 from waves 1..7 (slot wave-1), half1 from waves 0..6 (slot wave)
    if (wave != 0) {
        #pragma unroll
        for (int dt = 0; dt < 4; ++dt)
            #pragma unroll
            for (int j = 0; j < 4; ++j)
                CombO[0][wave - 1][c][dt * 16 + g * 4 + j] = f32_to_bf16(acc0[dt][j]);
        if (g == 0) { CombM[0][wave - 1][c] = m0; CombL[0][wave - 1][c] = l0; }
    }
    if (wave != 7) {
        #pragma unroll
        for (int dt = 0; dt < 4; ++dt)
            #pragma unroll
            for (int j = 0; j < 4; ++j)
                CombO[1][wave][c][dt * 16 + g * 4 + j] = f32_to_bf16(acc1[dt][j]);
        if (g == 0) { CombM[1][wave][c] = m1; CombL[1][wave][c] = l1; }
    }
    __syncthreads();

    auto FINAL = [&](int h, int rb, const float4v* aw, float mw, float lw) {
        float M = mw;
        #pragma unroll
        for (int s = 0; s < 7; ++s) M = fmaxf(M, CombM[h][s][c]);
        const float a0 = __expf(mw - M);
        float as[7];
        float lt = lw * a0;
        #pragma unroll
        for (int s = 0; s < 7; ++s) {
            as[s] = __expf(CombM[h][s][c] - M);
            lt += as[s] * CombL[h][s][c];
        }
        const float linv = 1.0f / lt;
        #pragma unroll
        for (int dt = 0; dt < 4; ++dt) {
            float4 o;
            float* op = &o.x;
            #pragma unroll
            for (int j = 0; j < 4; ++j) {
                float v = aw[dt][j] * a0;
                #pragma unroll
                for (int s = 0; s < 7; ++s)
                    v += as[s] * bf16_to_f32(CombO[h][s][c][dt * 16 + g * 4 + j]);
                op[j] = v * linv;
            }
            *(float4*)(out + bo + (size_t)(rb + c) * 64 + dt * 16 + g * 4) = o;
        }
    };

    if (wave == 0) FINAL(0, rb0, acc0, m0, l0);
    if (wave == 7) FINAL(1, rb1, acc1, m1, l1);
}

extern "C" void kernel_launch(void* const* d_in, const int* in_sizes, int n_in,
                              void* d_out, int out_size, void* d_ws, size_t ws_size,
                              hipStream_t stream) {
    const float* x  = (const float*)d_in[0];
    const float* Wq = (const float*)d_in[1];
    const float* Wk = (const float*)d_in[2];
    const float* Wv = (const float*)d_in[3];

    unsigned short* Wt = (unsigned short*)d_ws;                        // 384 KiB (frag-major)
    unsigned short* q  = (unsigned short*)((char*)d_ws + (size_t)3 * 65536 * 2);
    unsigned short* kp = q + (size_t)4 * T_LEN * HSZ;                  // frag-major K, 2 MiB
    unsigned short* vp = kp + (size_t)4 * T_LEN * HSZ;                 // frag-major V, 2 MiB
    float* out = (float*)d_out;

    hipLaunchKernelGGL(wt_kernel,  dim3(768), dim3(256), 0, stream, Wq, Wk, Wv, Wt);
    hipLaunchKernelGGL(qkv_kernel, dim3(512), dim3(512), 0, stream, x, Wt, q, kp, vp);
    hipLaunchKernelGGL(attn_kernel, dim3(512), dim3(512), 0, stream, q, kp, vp, out);
}